// Round 9
// baseline (92.685 us; speedup 1.0000x reference)
//
#include <hip/hip_runtime.h>

// Causal MHA forward: B=2 H=16 T=2048 DH=64, fp32 in/out, bf16 MFMA math.
// Flash-attention, 4 waves/block, wave owns 16 q rows, KBLK=64.
// Swapped QK^T (mfma(K,Q)); P in registers; V^T k-quad LDS layout.
// EQUAL-LENGTH STATIC SPLIT: block u<16 = A(p=u): qtile p complete (FINAL)
// + first 16-p k-tiles of qtile 31-p (PARTIAL side 0) = 17 iters.
// block u>=16 = B(p=u-16): last 16 k-tiles of qtile 31-p (PARTIAL side 1).
// All 1024 blocks run 16-17 iters -> steady ~16 waves/CU, no tail.
// Partials merged by a second kernel (r8 bug fixed: head = gr>>10).

constexpr int Bc = 2, Hc = 16, Tc = 2048, Dc = 64;
constexpr float QSCALE = 0.125f * 1.44269504088896340736f; // DH^-0.5 * log2 e

// ws layout: O-partials f32 [side][head][p][row 64][d 64], then ml
// [side][head][p][row 64][2].
constexpr size_t WS_O_FLOATS  = 2ull * 32 * 16 * 64 * 64;   // 4,194,304
constexpr size_t WS_ML_FLOATS = 2ull * 32 * 16 * 64 * 2;    //   131,072
constexpr size_t WS_NEED_BYTES = (WS_O_FLOATS + WS_ML_FLOATS) * 4;

typedef __attribute__((__ext_vector_type__(8))) __bf16 bf16x8;
typedef __attribute__((__ext_vector_type__(4))) __bf16 bf16x4;
typedef __attribute__((__ext_vector_type__(4))) float f32x4;

__global__ __launch_bounds__(256, 4) void attn_fwd_split(
    const float* __restrict__ Q,
    const float* __restrict__ K,
    const float* __restrict__ V,
    float* __restrict__ O,
    float* __restrict__ ws)
{
  const int tid  = threadIdx.x;
  const int wave = tid >> 6;
  const int lane = tid & 63;
  const int l16  = lane & 15;
  const int g    = lane >> 4;

  const int bid  = blockIdx.x;
  const int head = bid & 31;       // same head for a CU's static block set
  const int u    = bid >> 5;       // 0..31
  const int b = head >> 4, h = head & 15;
  const bool isA = (u < 16);
  const int p    = isA ? u : (u - 16);
  const int nseg = isA ? 2 : 1;

  const size_t hoff = (size_t)head * Tc * Dc;
  const float* Qb = Q + hoff;
  const float* Kb = K + hoff;
  const float* Vb = V + hoff;

  // K tile [64 k][64 d] bf16, 128 B rows, byte ^ ((k&7)<<4) swizzle.
  __shared__ __bf16 Kl[2][64 * 64];
  // V^T k-quads: addr(kc,d) = kc*512 + ((d*8) ^ (kc<<3) ^ (((d>>4)&3)<<3))
  // + 2*(k&3). Conflict-free b64 writes and floor reads.
  __shared__ __bf16 Vt[2][64 * 64];

  const int krow = tid >> 2;          // K staging: row; seg = 16-float chunk
  const int seg  = tid & 3;
  const int kswz = (krow & 7) << 4;
  const int vkb  = tid >> 4;          // V staging: k-quad block
  const int vdb  = tid & 15;          // V staging: d-quad
  const int vwx  = (vdb >> 2) << 3;

  float4 kreg[4], vreg[4];

  for (int sg = 0; sg < nseg; ++sg) {
    int qtile, klo, khi;
    bool fin;
    if (isA) {
      if (sg == 0) { qtile = p;      klo = 0;      khi = p + 1;  fin = true;  }
      else         { qtile = 31 - p; klo = 0;      khi = 16 - p; fin = false; }
    } else         { qtile = 31 - p; klo = 16 - p; khi = 32 - p; fin = false; }
    const int side = isA ? 0 : 1;
    const int q0 = qtile * 64 + wave * 16;

    __syncthreads();  // previous segment's LDS reads fully done

    // Q as B-operand frag of S^T = K·Q^T: lane l16 = q, regs d = c*32+g*8+j.
    bf16x8 qf[2];
    {
      const float4* qp = (const float4*)(Qb + (size_t)(q0 + l16) * Dc + g * 8);
      #pragma unroll
      for (int c = 0; c < 2; ++c) {
        float4 x0 = qp[c * 8], x1 = qp[c * 8 + 1];
        const float* f0 = (const float*)&x0;
        const float* f1 = (const float*)&x1;
        #pragma unroll
        for (int j = 0; j < 4; ++j) {
          qf[c][j]     = (__bf16)(f0[j] * QSCALE);
          qf[c][4 + j] = (__bf16)(f1[j] * QSCALE);
        }
      }
    }

    f32x4 o_acc[4] = {};
    float m_run = -1e30f, l_run = 0.f;

    // ---- Prologue: tile klo -> regs -> buf 0 ----
    {
      const float4* kp4 = (const float4*)(Kb + (size_t)(klo * 64 + krow) * Dc + seg * 16);
      #pragma unroll
      for (int c = 0; c < 4; ++c) kreg[c] = kp4[c];
      const float* vb0 = Vb + (size_t)(klo * 64 + vkb * 4) * Dc + vdb * 4;
      #pragma unroll
      for (int r = 0; r < 4; ++r) vreg[r] = *(const float4*)(vb0 + r * Dc);

      #pragma unroll
      for (int hh = 0; hh < 2; ++hh) {
        const float* x0 = (const float*)&kreg[2 * hh];
        const float* x1 = (const float*)&kreg[2 * hh + 1];
        bf16x8 t;
        #pragma unroll
        for (int j = 0; j < 4; ++j) { t[j] = (__bf16)x0[j]; t[4 + j] = (__bf16)x1[j]; }
        *(bf16x8*)((char*)Kl[0] + krow * 128 + ((seg * 32 + hh * 16) ^ kswz)) = t;
      }
      #pragma unroll
      for (int i = 0; i < 4; ++i) {
        bf16x4 t;
        #pragma unroll
        for (int r = 0; r < 4; ++r) t[r] = (__bf16)((const float*)&vreg[r])[i];
        const int d = vdb * 4 + i;
        *(bf16x4*)((char*)Vt[0] + vkb * 512 + ((d * 8) ^ (vkb << 3) ^ vwx)) = t;
      }
    }

    for (int it = klo; it < khi; ++it) {
      __syncthreads();  // buf[cur] staged; other buffer free
      const int ii  = it - klo;
      const int cur = ii & 1;

      // ---- T14: next tile's global loads land during compute ----
      const bool more = (it + 1 < khi);
      if (more) {
        const int kv1 = (it + 1) * 64;
        const float4* kp4 = (const float4*)(Kb + (size_t)(kv1 + krow) * Dc + seg * 16);
        #pragma unroll
        for (int c = 0; c < 4; ++c) kreg[c] = kp4[c];
        const float* vb0 = Vb + (size_t)(kv1 + vkb * 4) * Dc + vdb * 4;
        #pragma unroll
        for (int r = 0; r < 4; ++r) vreg[r] = *(const float4*)(vb0 + r * Dc);
      }

      const bool partial = (it == qtile);
      const int  ns = partial ? (wave + 1) : 4;

      // ---- S^T = K·Q^T: sacc[s] k = s*16+g*4+r, q = l16 ----
      f32x4 sacc[4];
      __builtin_amdgcn_s_setprio(1);
      #pragma unroll
      for (int s = 0; s < 4; ++s) {
        if (s < ns) {  // wave-uniform
          f32x4 z = {0.f, 0.f, 0.f, 0.f};
          const int row = s * 16 + l16;
          const char* kb = (const char*)Kl[cur] + row * 128;
          const int swz = (row & 7) << 4;
          bf16x8 k0 = *(const bf16x8*)(kb + ((g * 16) ^ swz));
          bf16x8 k1 = *(const bf16x8*)(kb + ((64 + g * 16) ^ swz));
          z = __builtin_amdgcn_mfma_f32_16x16x32_bf16(k0, qf[0], z, 0, 0, 0);
          z = __builtin_amdgcn_mfma_f32_16x16x32_bf16(k1, qf[1], z, 0, 0, 0);
          sacc[s] = z;
        } else {
          sacc[s] = f32x4{-INFINITY, -INFINITY, -INFINITY, -INFINITY};
        }
      }
      __builtin_amdgcn_s_setprio(0);
      if (partial) {  // diagonal mask
        #pragma unroll
        for (int s = 0; s < 4; ++s)
          #pragma unroll
          for (int r = 0; r < 4; ++r)
            if (s * 16 + g * 4 + r > wave * 16 + l16) sacc[s][r] = -INFINITY;
      }

      // ---- Online softmax for q-row l16 (4 g-replicas), tree reduce ----
      float v16[16];
      #pragma unroll
      for (int s = 0; s < 4; ++s)
        #pragma unroll
        for (int r = 0; r < 4; ++r) v16[s * 4 + r] = sacc[s][r];
      #pragma unroll
      for (int w = 8; w >= 1; w >>= 1)
        #pragma unroll
        for (int i = 0; i < 8; ++i)
          if (i < w) v16[i] = fmaxf(v16[i], v16[i + w]);
      float mx = v16[0];
      mx = fmaxf(mx, __shfl_xor(mx, 16, 64));
      mx = fmaxf(mx, __shfl_xor(mx, 32, 64));

      // T13 defer-max: skip rescale while max growth < 8.
      if (!__all(mx <= m_run + 8.0f)) {
        const float mn = fmaxf(m_run, mx);
        const float f  = __builtin_amdgcn_exp2f(m_run - mn);
        m_run = mn;
        l_run *= f;
        #pragma unroll
        for (int r = 0; r < 4; ++r) {
          const float fo = __shfl(f, g * 4 + r, 64);
          #pragma unroll
          for (int dt = 0; dt < 4; ++dt) o_acc[dt][r] *= fo;
        }
      }

      float pv16[16];
      bf16x8 pa[2];
      #pragma unroll
      for (int c = 0; c < 2; ++c)
        #pragma unroll
        for (int j = 0; j < 8; ++j) {
          const float pv = __builtin_amdgcn_exp2f(sacc[2 * c + (j >> 2)][j & 3] - m_run);
          pv16[c * 8 + j] = pv;
          pa[c][j] = (__bf16)pv;
        }
      #pragma unroll
      for (int w = 8; w >= 1; w >>= 1)
        #pragma unroll
        for (int i = 0; i < 8; ++i)
          if (i < w) pv16[i] += pv16[i + w];
      float sum = pv16[0];
      sum += __shfl_xor(sum, 16, 64);
      sum += __shfl_xor(sum, 32, 64);
      l_run += sum;

      // ---- PV: O += P(16x64)·V(64x64), both operands in pi k-order ----
      __builtin_amdgcn_s_setprio(1);
      #pragma unroll
      for (int dt = 0; dt < 4; ++dt) {
        const int d = dt * 16 + l16;
        const int dx = (dt & 3) << 3;
        #pragma unroll
        for (int c = 0; c < 2; ++c) {
          const int kc0 = 8 * c + g;
          const int kc1 = 8 * c + 4 + g;
          union { bf16x8 v8; bf16x4 v4[2]; } uu;
          uu.v4[0] = *(const bf16x4*)((char*)Vt[cur] + kc0 * 512 + ((d * 8) ^ (kc0 << 3) ^ dx));
          uu.v4[1] = *(const bf16x4*)((char*)Vt[cur] + kc1 * 512 + ((d * 8) ^ (kc1 << 3) ^ dx));
          o_acc[dt] = __builtin_amdgcn_mfma_f32_16x16x32_bf16(pa[c], uu.v8, o_acc[dt], 0, 0, 0);
        }
      }
      __builtin_amdgcn_s_setprio(0);

      // ---- Write prefetched tile into the other buffer ----
      if (more) {
        const int nxt = cur ^ 1;
        #pragma unroll
        for (int hh = 0; hh < 2; ++hh) {
          const float* x0 = (const float*)&kreg[2 * hh];
          const float* x1 = (const float*)&kreg[2 * hh + 1];
          bf16x8 t;
          #pragma unroll
          for (int j = 0; j < 4; ++j) { t[j] = (__bf16)x0[j]; t[4 + j] = (__bf16)x1[j]; }
          *(bf16x8*)((char*)Kl[nxt] + krow * 128 + ((seg * 32 + hh * 16) ^ kswz)) = t;
        }
        #pragma unroll
        for (int i = 0; i < 4; ++i) {
          bf16x4 t;
          #pragma unroll
          for (int r = 0; r < 4; ++r) t[r] = (__bf16)((const float*)&vreg[r])[i];
          const int d = vdb * 4 + i;
          *(bf16x4*)((char*)Vt[nxt] + vkb * 512 + ((d * 8) ^ (vkb << 3) ^ vwx)) = t;
        }
      }
    }

    if (fin) {
      // ---- FINAL: out[b][q][h*64+d] = o / l ----
      #pragma unroll
      for (int r = 0; r < 4; ++r) {
        const float il = __shfl(l_run, g * 4 + r, 64);
        const float inv = 1.f / il;
        float* orow = O + ((size_t)b * Tc + (q0 + g * 4 + r)) * (Hc * Dc) + h * Dc;
        #pragma unroll
        for (int dt = 0; dt < 4; ++dt)
          orow[dt * 16 + l16] = o_acc[dt][r] * inv;
      }
    } else {
      // ---- PARTIAL: unnormalized O + (m,l) to ws ----
      float* wsO  = ws;
      float* wsML = ws + WS_O_FLOATS;
      const size_t base = (((size_t)side * 32 + head) * 16 + p) * 64;
      #pragma unroll
      for (int r = 0; r < 4; ++r) {
        const int row = wave * 16 + g * 4 + r;
        #pragma unroll
        for (int dt = 0; dt < 4; ++dt)
          wsO[(base + row) * 64 + dt * 16 + l16] = o_acc[dt][r];
      }
      if (g == 0) {
        const size_t mlb = (base + wave * 16 + l16) * 2;
        wsML[mlb]     = m_run;
        wsML[mlb + 1] = l_run;
      }
    }
  }
}

// Merge: final O rows for qtiles 16..31. Block = 4 rows x 64 d-threads.
// 32768 rows total = 32 heads x 16 p x 64 rows -> head = gr>>10 (r8 fix).
__global__ __launch_bounds__(256) void attn_merge(
    const float* __restrict__ ws, float* __restrict__ O)
{
  const int gr = blockIdx.x * 4 + (threadIdx.x >> 6); // 0..32767
  const int d  = threadIdx.x & 63;
  const int head = gr >> 10;        // 1024 rows per head (16 p x 64 rows)
  const int p    = (gr >> 6) & 15;
  const int row  = gr & 63;
  const int qrow = (31 - p) * 64 + row;
  const int b = head >> 4, h = head & 15;

  const float* wsO  = ws;
  const float* wsML = ws + WS_O_FLOATS;
  const size_t bA = (((size_t)0 * 32 + head) * 16 + p) * 64 + row;
  const size_t bB = (((size_t)1 * 32 + head) * 16 + p) * 64 + row;

  const float mA = wsML[bA * 2], lA = wsML[bA * 2 + 1];
  const float mB = wsML[bB * 2], lB = wsML[bB * 2 + 1];
  const float m  = fmaxf(mA, mB);
  const float wA = __builtin_amdgcn_exp2f(mA - m);
  const float wB = __builtin_amdgcn_exp2f(mB - m);
  const float inv = 1.f / (wA * lA + wB * lB);

  const float o = (wA * wsO[bA * 64 + d] + wB * wsO[bB * 64 + d]) * inv;
  O[((size_t)b * Tc + qrow) * (Hc * Dc) + h * 64 + d] = o;
}

// ---------------- Fallback (proven round-6 kernel, ws-free) ----------------
__global__ __launch_bounds__(256, 4) void attn_fwd_kernel(
    const float* __restrict__ Q,
    const float* __restrict__ K,
    const float* __restrict__ V,
    float* __restrict__ O)
{
  const int tid  = threadIdx.x;
  const int wave = tid >> 6;
  const int lane = tid & 63;
  const int l16  = lane & 15;
  const int g    = lane >> 4;

  const int bid   = blockIdx.x;
  const int head  = bid & 31;
  const int qtile = 31 - (bid >> 5);
  const int b = head >> 4, h = head & 15;
  const int q0 = qtile * 64 + wave * 16;

  const size_t hoff = (size_t)head * Tc * Dc;
  const float* Qb = Q + hoff;
  const float* Kb = K + hoff;
  const float* Vb = V + hoff;

  __shared__ __bf16 Kl[2][64 * 64];
  __shared__ __bf16 Vt[2][64 * 64];

  const int krow = tid >> 2;
  const int seg  = tid & 3;
  const int kswz = (krow & 7) << 4;
  const int vkb  = tid >> 4;
  const int vdb  = tid & 15;
  const int vwx  = (vdb >> 2) << 3;

  bf16x8 qf[2];
  {
    const float4* qp = (const float4*)(Qb + (size_t)(q0 + l16) * Dc + g * 8);
    #pragma unroll
    for (int c = 0; c < 2; ++c) {
      float4 x0 = qp[c * 8], x1 = qp[c * 8 + 1];
      const float* f0 = (const float*)&x0;
      const float* f1 = (const float*)&x1;
      #pragma unroll
      for (int j = 0; j < 4; ++j) {
        qf[c][j]     = (__bf16)(f0[j] * QSCALE);
        qf[c][4 + j] = (__bf16)(f1[j] * QSCALE);
      }
    }
  }

  f32x4 o_acc[4] = {};
  float m_run = -1e30f, l_run = 0.f;
  const int n_iter = qtile + 1;
  float4 kreg[4], vreg[4];

  {
    const float4* kp4 = (const float4*)(Kb + (size_t)krow * Dc + seg * 16);
    #pragma unroll
    for (int c = 0; c < 4; ++c) kreg[c] = kp4[c];
    const float* vb0 = Vb + (size_t)(vkb * 4) * Dc + vdb * 4;
    #pragma unroll
    for (int r = 0; r < 4; ++r) vreg[r] = *(const float4*)(vb0 + r * Dc);

    #pragma unroll
    for (int hh = 0; hh < 2; ++hh) {
      const float* x0 = (const float*)&kreg[2 * hh];
      const float* x1 = (const float*)&kreg[2 * hh + 1];
      bf16x8 t;
      #pragma unroll
      for (int j = 0; j < 4; ++j) { t[j] = (__bf16)x0[j]; t[4 + j] = (__bf16)x1[j]; }
      *(bf16x8*)((char*)Kl[0] + krow * 128 + ((seg * 32 + hh * 16) ^ kswz)) = t;
    }
    #pragma unroll
    for (int i = 0; i < 4; ++i) {
      bf16x4 t;
      #pragma unroll
      for (int r = 0; r < 4; ++r) t[r] = (__bf16)((const float*)&vreg[r])[i];
      const int d = vdb * 4 + i;
      *(bf16x4*)((char*)Vt[0] + vkb * 512 + ((d * 8) ^ (vkb << 3) ^ vwx)) = t;
    }
  }

  for (int it = 0; it < n_iter; ++it) {
    __syncthreads();
    const int cur = it & 1;
    const bool more = (it + 1 < n_iter);
    if (more) {
      const int kv1 = (it + 1) * 64;
      const float4* kp4 = (const float4*)(Kb + (size_t)(kv1 + krow) * Dc + seg * 16);
      #pragma unroll
      for (int c = 0; c < 4; ++c) kreg[c] = kp4[c];
      const float* vb0 = Vb + (size_t)(kv1 + vkb * 4) * Dc + vdb * 4;
      #pragma unroll
      for (int r = 0; r < 4; ++r) vreg[r] = *(const float4*)(vb0 + r * Dc);
    }

    const bool partial = (it == qtile);
    const int  ns = partial ? (wave + 1) : 4;

    f32x4 sacc[4];
    __builtin_amdgcn_s_setprio(1);
    #pragma unroll
    for (int s = 0; s < 4; ++s) {
      if (s < ns) {
        f32x4 z = {0.f, 0.f, 0.f, 0.f};
        const int row = s * 16 + l16;
        const char* kb = (const char*)Kl[cur] + row * 128;
        const int swz = (row & 7) << 4;
        bf16x8 k0 = *(const bf16x8*)(kb + ((g * 16) ^ swz));
        bf16x8 k1 = *(const bf16x8*)(kb + ((64 + g * 16) ^ swz));
        z = __builtin_amdgcn_mfma_f32_16x16x32_bf16(k0, qf[0], z, 0, 0, 0);
        z = __builtin_amdgcn_mfma_f32_16x16x32_bf16(k1, qf[1], z, 0, 0, 0);
        sacc[s] = z;
      } else {
        sacc[s] = f32x4{-INFINITY, -INFINITY, -INFINITY, -INFINITY};
      }
    }
    __builtin_amdgcn_s_setprio(0);
    if (partial) {
      #pragma unroll
      for (int s = 0; s < 4; ++s)
        #pragma unroll
        for (int r = 0; r < 4; ++r)
          if (s * 16 + g * 4 + r > wave * 16 + l16) sacc[s][r] = -INFINITY;
    }

    float v16[16];
    #pragma unroll
    for (int s = 0; s < 4; ++s)
      #pragma unroll
      for (int r = 0; r < 4; ++r) v16[s * 4 + r] = sacc[s][r];
    #pragma unroll
    for (int w = 8; w >= 1; w >>= 1)
      #pragma unroll
      for (int i = 0; i < 8; ++i)
        if (i < w) v16[i] = fmaxf(v16[i], v16[i + w]);
    float mx = v16[0];
    mx = fmaxf(mx, __shfl_xor(mx, 16, 64));
    mx = fmaxf(mx, __shfl_xor(mx, 32, 64));

    if (!__all(mx <= m_run + 8.0f)) {
      const float mn = fmaxf(m_run, mx);
      const float f  = __builtin_amdgcn_exp2f(m_run - mn);
      m_run = mn;
      l_run *= f;
      #pragma unroll
      for (int r = 0; r < 4; ++r) {
        const float fo = __shfl(f, g * 4 + r, 64);
        #pragma unroll
        for (int dt = 0; dt < 4; ++dt) o_acc[dt][r] *= fo;
      }
    }

    float pv16[16];
    bf16x8 pa[2];
    #pragma unroll
    for (int c = 0; c < 2; ++c)
      #pragma unroll
      for (int j = 0; j < 8; ++j) {
        const float pv = __builtin_amdgcn_exp2f(sacc[2 * c + (j >> 2)][j & 3] - m_run);
        pv16[c * 8 + j] = pv;
        pa[c][j] = (__bf16)pv;
      }
    #pragma unroll
    for (int w = 8; w >= 1; w >>= 1)
      #pragma unroll
      for (int i = 0; i < 8; ++i)
        if (i < w) pv16[i] += pv16[i + w];
    float sum = pv16[0];
    sum += __shfl_xor(sum, 16, 64);
    sum += __shfl_xor(sum, 32, 64);
    l_run += sum;

    __builtin_amdgcn_s_setprio(1);
    #pragma unroll
    for (int dt = 0; dt < 4; ++dt) {
      const int d = dt * 16 + l16;
      const int dx = (dt & 3) << 3;
      #pragma unroll
      for (int c = 0; c < 2; ++c) {
        const int kc0 = 8 * c + g;
        const int kc1 = 8 * c + 4 + g;
        union { bf16x8 v8; bf16x4 v4[2]; } uu;
        uu.v4[0] = *(const bf16x4*)((char*)Vt[cur] + kc0 * 512 + ((d * 8) ^ (kc0 << 3) ^ dx));
        uu.v4[1] = *(const bf16x4*)((char*)Vt[cur] + kc1 * 512 + ((d * 8) ^ (kc1 << 3) ^ dx));
        o_acc[dt] = __builtin_amdgcn_mfma_f32_16x16x32_bf16(pa[c], uu.v8, o_acc[dt], 0, 0, 0);
      }
    }
    __builtin_amdgcn_s_setprio(0);

    if (more) {
      const int nxt = cur ^ 1;
      #pragma unroll
      for (int hh = 0; hh < 2; ++hh) {
        const float* x0 = (const float*)&kreg[2 * hh];
        const float* x1 = (const float*)&kreg[2 * hh + 1];
        bf16x8 t;
        #pragma unroll
        for (int j = 0; j < 4; ++j) { t[j] = (__bf16)x0[j]; t[4 + j] = (__bf16)x1[j]; }
        *(bf16x8*)((char*)Kl[nxt] + krow * 128 + ((seg * 32 + hh * 16) ^ kswz)) = t;
      }
      #pragma unroll
      for (int i = 0; i < 4; ++i) {
        bf16x4 t;
        #pragma unroll
        for (int r = 0; r < 4; ++r) t[r] = (__bf16)((const float*)&vreg[r])[i];
        const int d = vdb * 4 + i;
        *(bf16x4*)((char*)Vt[nxt] + vkb * 512 + ((d * 8) ^ (vkb << 3) ^ vwx)) = t;
      }
    }
  }

  #pragma unroll
  for (int r = 0; r < 4; ++r) {
    const float il = __shfl(l_run, g * 4 + r, 64);
    const float inv = 1.f / il;
    float* orow = O + ((size_t)b * Tc + (q0 + g * 4 + r)) * (Hc * Dc) + h * Dc;
    #pragma unroll
    for (int dt = 0; dt < 4; ++dt)
      orow[dt * 16 + l16] = o_acc[dt][r] * inv;
  }
}

extern "C" void kernel_launch(void* const* d_in, const int* in_sizes, int n_in,
                              void* d_out, int out_size, void* d_ws, size_t ws_size,
                              hipStream_t stream) {
  const float* q = (const float*)d_in[0];
  const float* k = (const float*)d_in[1];
  const float* v = (const float*)d_in[2];
  float* out = (float*)d_out;

  if (ws_size >= WS_NEED_BYTES) {
    hipLaunchKernelGGL(attn_fwd_split, dim3(1024), dim3(256), 0, stream,
                       q, k, v, out, (float*)d_ws);
    hipLaunchKernelGGL(attn_merge, dim3(8192), dim3(256), 0, stream,
                       (float*)d_ws, out);
  } else {
    hipLaunchKernelGGL(attn_fwd_kernel, dim3(1024), dim3(256), 0, stream,
                       q, k, v, out);
  }
}

// Round 10
// 53.156 us; speedup vs baseline: 1.7436x; 1.7436x over previous
//
#include <hip/hip_runtime.h>

// Causal MHA forward: B=2 H=16 T=2048 DH=64, fp32 in/out, bf16 MFMA math.
// Round-6 schedule (grid 1024 LPT, 4 waves, KBLK=64, dbuf, 1 barrier/iter)
// + bf16 PRE-PASS: conv_k writes K as bf16 with the LDS XOR-swizzle baked
// into the global layout; conv_v writes V^T in the k-quad swizzled layout.
// Main-loop staging is then a linear 16B-stride copy: no cvt, no transpose,
// conflict-free ds_write_b128, loop-invariant LDS addresses.

constexpr int Bc = 2, Hc = 16, Tc = 2048, Dc = 64;
constexpr float QSCALE = 0.125f * 1.44269504088896340736f; // DH^-0.5 * log2 e

// ws: K16 [head][k][swizzled 128B row] (256 KB/head), then Vq (256 KB/head).
constexpr size_t WS_K_BYTES = 32ull * 2048 * 128;  // 8 MB
constexpr size_t WS_V_BYTES = 32ull * 2048 * 128;  // 8 MB
constexpr size_t WS_NEED_BYTES = WS_K_BYTES + WS_V_BYTES;

typedef __attribute__((__ext_vector_type__(8))) __bf16 bf16x8;
typedef __attribute__((__ext_vector_type__(4))) __bf16 bf16x4;
typedef __attribute__((__ext_vector_type__(4))) float f32x4;

// ---- Pre-pass: K fp32 -> bf16, XOR-swizzle baked ((c16*16) ^ ((k&7)<<4)) --
__global__ __launch_bounds__(256) void conv_k(
    const float* __restrict__ K, __bf16* __restrict__ KO)
{
  const int i = blockIdx.x * 256 + threadIdx.x;   // 524288 threads
  const int c16  = i & 7;
  const int k    = (i >> 3) & 2047;
  const int head = i >> 14;
  const float* src = K + ((size_t)head * 2048 + k) * 64 + c16 * 8;
  float4 a = *(const float4*)src, b = *(const float4*)(src + 4);
  bf16x8 t;
  const float* fa = (const float*)&a;
  const float* fb = (const float*)&b;
  #pragma unroll
  for (int j = 0; j < 4; ++j) { t[j] = (__bf16)fa[j]; t[4 + j] = (__bf16)fb[j]; }
  char* dst = (char*)KO + (size_t)head * 262144 + k * 128 + ((c16 * 16) ^ ((k & 7) << 4));
  *(bf16x8*)dst = t;
}

// ---- Pre-pass: V fp32 -> bf16 transposed k-quads, swizzle baked ----
// addr(tile, kcl, d, kin) = tile*8192 + kcl*512 + ((d*8)^(kcl<<3)^(((d>>4)&3)<<3)) + kin*2
__global__ __launch_bounds__(256) void conv_v(
    const float* __restrict__ V, __bf16* __restrict__ VO)
{
  const int i = blockIdx.x * 256 + threadIdx.x;   // 1048576 threads
  const int d    = i & 63;
  const int kc   = (i >> 6) & 511;
  const int head = i >> 15;
  const float* src = V + ((size_t)head * 2048 + kc * 4) * 64 + d;
  bf16x4 t = { (__bf16)src[0], (__bf16)src[64], (__bf16)src[128], (__bf16)src[192] };
  const int itv = kc >> 4, kcl = kc & 15;
  const int dx  = ((d >> 4) & 3) << 3;
  char* dst = (char*)VO + (size_t)head * 262144 + itv * 8192 + kcl * 512
            + ((d * 8) ^ (kcl << 3) ^ dx);
  *(bf16x4*)dst = t;
}

// ---------------- Main kernel (round-6 schedule, bf16 staging) -------------
__global__ __launch_bounds__(256, 4) void attn_fwd_bf16s(
    const float* __restrict__ Q,
    const __bf16* __restrict__ K16,
    const __bf16* __restrict__ Vq,
    float* __restrict__ O)
{
  const int tid  = threadIdx.x;
  const int wave = tid >> 6;
  const int lane = tid & 63;
  const int l16  = lane & 15;
  const int g    = lane >> 4;

  const int bid   = blockIdx.x;
  const int head  = bid & 31;           // co-resident blocks share head
  const int qtile = 31 - (bid >> 5);    // LPT: longest first
  const int b = head >> 4, h = head & 15;
  const int q0 = qtile * 64 + wave * 16;

  const float* Qb = Q + (size_t)head * Tc * Dc;
  const char*  Kb = (const char*)K16 + (size_t)head * 262144;
  const char*  Vb = (const char*)Vq  + (size_t)head * 262144;

  __shared__ __bf16 Kl[2][4096];   // 8 KB swizzled K tile per buffer
  __shared__ __bf16 Vt[2][4096];   // 8 KB swizzled V^T tile per buffer

  // Q as B-operand frag of S^T = K·Q^T: lane l16 = q, regs d = c*32+g*8+j.
  bf16x8 qf[2];
  {
    const float4* qp = (const float4*)(Qb + (size_t)(q0 + l16) * Dc + g * 8);
    #pragma unroll
    for (int c = 0; c < 2; ++c) {
      float4 x0 = qp[c * 8], x1 = qp[c * 8 + 1];
      const float* f0 = (const float*)&x0;
      const float* f1 = (const float*)&x1;
      #pragma unroll
      for (int j = 0; j < 4; ++j) {
        qf[c][j]     = (__bf16)(f0[j] * QSCALE);
        qf[c][4 + j] = (__bf16)(f1[j] * QSCALE);
      }
    }
  }

  f32x4 o_acc[4] = {};
  float m_run = -1e30f, l_run = 0.f;
  const int n_iter = qtile + 1;

  bf16x8 ks[2], vs[2];

  // ---- Prologue: tile 0 -> regs -> buf 0 (linear 16B-stride copy) ----
  {
    ks[0] = *(const bf16x8*)(Kb + tid * 16);
    ks[1] = *(const bf16x8*)(Kb + 4096 + tid * 16);
    vs[0] = *(const bf16x8*)(Vb + tid * 16);
    vs[1] = *(const bf16x8*)(Vb + 4096 + tid * 16);
    *(bf16x8*)((char*)Kl[0] + tid * 16)        = ks[0];
    *(bf16x8*)((char*)Kl[0] + 4096 + tid * 16) = ks[1];
    *(bf16x8*)((char*)Vt[0] + tid * 16)        = vs[0];
    *(bf16x8*)((char*)Vt[0] + 4096 + tid * 16) = vs[1];
  }

  for (int it = 0; it < n_iter; ++it) {
    __syncthreads();   // buf[cur] staged; other buffer free
    const int cur = it & 1;

    // ---- T14: next tile's global loads land during compute ----
    const bool more = (it + 1 < n_iter);
    if (more) {
      const char* kb2 = Kb + (size_t)(it + 1) * 8192;
      const char* vb2 = Vb + (size_t)(it + 1) * 8192;
      ks[0] = *(const bf16x8*)(kb2 + tid * 16);
      ks[1] = *(const bf16x8*)(kb2 + 4096 + tid * 16);
      vs[0] = *(const bf16x8*)(vb2 + tid * 16);
      vs[1] = *(const bf16x8*)(vb2 + 4096 + tid * 16);
    }

    const bool partial = (it == qtile);
    const int  ns = partial ? (wave + 1) : 4;

    // ---- S^T = K·Q^T: sacc[s] k = s*16+g*4+r, q = l16 ----
    f32x4 sacc[4];
    __builtin_amdgcn_s_setprio(1);
    #pragma unroll
    for (int s = 0; s < 4; ++s) {
      if (s < ns) {  // wave-uniform
        f32x4 z = {0.f, 0.f, 0.f, 0.f};
        const int row = s * 16 + l16;
        const char* kb = (const char*)Kl[cur] + row * 128;
        const int swz = (row & 7) << 4;
        bf16x8 k0 = *(const bf16x8*)(kb + ((g * 16) ^ swz));
        bf16x8 k1 = *(const bf16x8*)(kb + ((64 + g * 16) ^ swz));
        z = __builtin_amdgcn_mfma_f32_16x16x32_bf16(k0, qf[0], z, 0, 0, 0);
        z = __builtin_amdgcn_mfma_f32_16x16x32_bf16(k1, qf[1], z, 0, 0, 0);
        sacc[s] = z;
      } else {
        sacc[s] = f32x4{-INFINITY, -INFINITY, -INFINITY, -INFINITY};
      }
    }
    __builtin_amdgcn_s_setprio(0);
    if (partial) {  // diagonal mask
      #pragma unroll
      for (int s = 0; s < 4; ++s)
        #pragma unroll
        for (int r = 0; r < 4; ++r)
          if (s * 16 + g * 4 + r > wave * 16 + l16) sacc[s][r] = -INFINITY;
    }

    // ---- Online softmax for q-row l16 (4 g-replicas), tree reduce ----
    float v16[16];
    #pragma unroll
    for (int s = 0; s < 4; ++s)
      #pragma unroll
      for (int r = 0; r < 4; ++r) v16[s * 4 + r] = sacc[s][r];
    #pragma unroll
    for (int w = 8; w >= 1; w >>= 1)
      #pragma unroll
      for (int i = 0; i < 8; ++i)
        if (i < w) v16[i] = fmaxf(v16[i], v16[i + w]);
    float mx = v16[0];
    mx = fmaxf(mx, __shfl_xor(mx, 16, 64));
    mx = fmaxf(mx, __shfl_xor(mx, 32, 64));

    // T13 defer-max: skip rescale while max growth < 8.
    if (!__all(mx <= m_run + 8.0f)) {
      const float mn = fmaxf(m_run, mx);
      const float f  = __builtin_amdgcn_exp2f(m_run - mn);
      m_run = mn;
      l_run *= f;
      #pragma unroll
      for (int r = 0; r < 4; ++r) {
        const float fo = __shfl(f, g * 4 + r, 64);
        #pragma unroll
        for (int dt = 0; dt < 4; ++dt) o_acc[dt][r] *= fo;
      }
    }

    float pv16[16];
    bf16x8 pa[2];
    #pragma unroll
    for (int c = 0; c < 2; ++c)
      #pragma unroll
      for (int j = 0; j < 8; ++j) {
        const float pv = __builtin_amdgcn_exp2f(sacc[2 * c + (j >> 2)][j & 3] - m_run);
        pv16[c * 8 + j] = pv;
        pa[c][j] = (__bf16)pv;
      }
    #pragma unroll
    for (int w = 8; w >= 1; w >>= 1)
      #pragma unroll
      for (int i = 0; i < 8; ++i)
        if (i < w) pv16[i] += pv16[i + w];
    float sum = pv16[0];
    sum += __shfl_xor(sum, 16, 64);
    sum += __shfl_xor(sum, 32, 64);
    l_run += sum;

    // ---- PV: O += P(16x64)·V(64x64), both operands in pi k-order ----
    __builtin_amdgcn_s_setprio(1);
    #pragma unroll
    for (int dt = 0; dt < 4; ++dt) {
      const int d = dt * 16 + l16;
      const int dx = (dt & 3) << 3;
      #pragma unroll
      for (int c = 0; c < 2; ++c) {
        const int kc0 = 8 * c + g;
        const int kc1 = 8 * c + 4 + g;
        union { bf16x8 v8; bf16x4 v4[2]; } uu;
        uu.v4[0] = *(const bf16x4*)((char*)Vt[cur] + kc0 * 512 + ((d * 8) ^ (kc0 << 3) ^ dx));
        uu.v4[1] = *(const bf16x4*)((char*)Vt[cur] + kc1 * 512 + ((d * 8) ^ (kc1 << 3) ^ dx));
        o_acc[dt] = __builtin_amdgcn_mfma_f32_16x16x32_bf16(pa[c], uu.v8, o_acc[dt], 0, 0, 0);
      }
    }
    __builtin_amdgcn_s_setprio(0);

    // ---- Write prefetched tile into the other buffer (linear copy) ----
    if (more) {
      const int nxt = cur ^ 1;
      *(bf16x8*)((char*)Kl[nxt] + tid * 16)        = ks[0];
      *(bf16x8*)((char*)Kl[nxt] + 4096 + tid * 16) = ks[1];
      *(bf16x8*)((char*)Vt[nxt] + tid * 16)        = vs[0];
      *(bf16x8*)((char*)Vt[nxt] + 4096 + tid * 16) = vs[1];
    }
  }

  // ---- Epilogue: out[b][q][h*64+d] = o / l ----
  #pragma unroll
  for (int r = 0; r < 4; ++r) {
    const float il = __shfl(l_run, g * 4 + r, 64);
    const float inv = 1.f / il;
    float* orow = O + ((size_t)b * Tc + (q0 + g * 4 + r)) * (Hc * Dc) + h * Dc;
    #pragma unroll
    for (int dt = 0; dt < 4; ++dt)
      orow[dt * 16 + l16] = o_acc[dt][r] * inv;
  }
}

// -------- Fallback (round-6 kernel, fp32 staging, ws-free) --------
__global__ __launch_bounds__(256, 4) void attn_fwd_kernel(
    const float* __restrict__ Q,
    const float* __restrict__ K,
    const float* __restrict__ V,
    float* __restrict__ O)
{
  const int tid  = threadIdx.x;
  const int wave = tid >> 6;
  const int lane = tid & 63;
  const int l16  = lane & 15;
  const int g    = lane >> 4;

  const int bid   = blockIdx.x;
  const int head  = bid & 31;
  const int qtile = 31 - (bid >> 5);
  const int b = head >> 4, h = head & 15;
  const int q0 = qtile * 64 + wave * 16;

  const size_t hoff = (size_t)head * Tc * Dc;
  const float* Qb = Q + hoff;
  const float* Kb = K + hoff;
  const float* Vb = V + hoff;

  __shared__ __bf16 Kl[2][64 * 64];
  __shared__ __bf16 Vt[2][64 * 64];

  const int krow = tid >> 2;
  const int seg  = tid & 3;
  const int kswz = (krow & 7) << 4;
  const int vkb  = tid >> 4;
  const int vdb  = tid & 15;
  const int vwx  = (vdb >> 2) << 3;

  bf16x8 qf[2];
  {
    const float4* qp = (const float4*)(Qb + (size_t)(q0 + l16) * Dc + g * 8);
    #pragma unroll
    for (int c = 0; c < 2; ++c) {
      float4 x0 = qp[c * 8], x1 = qp[c * 8 + 1];
      const float* f0 = (const float*)&x0;
      const float* f1 = (const float*)&x1;
      #pragma unroll
      for (int j = 0; j < 4; ++j) {
        qf[c][j]     = (__bf16)(f0[j] * QSCALE);
        qf[c][4 + j] = (__bf16)(f1[j] * QSCALE);
      }
    }
  }

  f32x4 o_acc[4] = {};
  float m_run = -1e30f, l_run = 0.f;
  const int n_iter = qtile + 1;
  float4 kreg[4], vreg[4];

  {
    const float4* kp4 = (const float4*)(Kb + (size_t)krow * Dc + seg * 16);
    #pragma unroll
    for (int c = 0; c < 4; ++c) kreg[c] = kp4[c];
    const float* vb0 = Vb + (size_t)(vkb * 4) * Dc + vdb * 4;
    #pragma unroll
    for (int r = 0; r < 4; ++r) vreg[r] = *(const float4*)(vb0 + r * Dc);

    #pragma unroll
    for (int hh = 0; hh < 2; ++hh) {
      const float* x0 = (const float*)&kreg[2 * hh];
      const float* x1 = (const float*)&kreg[2 * hh + 1];
      bf16x8 t;
      #pragma unroll
      for (int j = 0; j < 4; ++j) { t[j] = (__bf16)x0[j]; t[4 + j] = (__bf16)x1[j]; }
      *(bf16x8*)((char*)Kl[0] + krow * 128 + ((seg * 32 + hh * 16) ^ kswz)) = t;
    }
    #pragma unroll
    for (int i = 0; i < 4; ++i) {
      bf16x4 t;
      #pragma unroll
      for (int r = 0; r < 4; ++r) t[r] = (__bf16)((const float*)&vreg[r])[i];
      const int d = vdb * 4 + i;
      *(bf16x4*)((char*)Vt[0] + vkb * 512 + ((d * 8) ^ (vkb << 3) ^ vwx)) = t;
    }
  }

  for (int it = 0; it < n_iter; ++it) {
    __syncthreads();
    const int cur = it & 1;
    const bool more = (it + 1 < n_iter);
    if (more) {
      const int kv1 = (it + 1) * 64;
      const float4* kp4 = (const float4*)(Kb + (size_t)(kv1 + krow) * Dc + seg * 16);
      #pragma unroll
      for (int c = 0; c < 4; ++c) kreg[c] = kp4[c];
      const float* vb0 = Vb + (size_t)(kv1 + vkb * 4) * Dc + vdb * 4;
      #pragma unroll
      for (int r = 0; r < 4; ++r) vreg[r] = *(const float4*)(vb0 + r * Dc);
    }

    const bool partial = (it == qtile);
    const int  ns = partial ? (wave + 1) : 4;

    f32x4 sacc[4];
    __builtin_amdgcn_s_setprio(1);
    #pragma unroll
    for (int s = 0; s < 4; ++s) {
      if (s < ns) {
        f32x4 z = {0.f, 0.f, 0.f, 0.f};
        const int row = s * 16 + l16;
        const char* kb = (const char*)Kl[cur] + row * 128;
        const int swz = (row & 7) << 4;
        bf16x8 k0 = *(const bf16x8*)(kb + ((g * 16) ^ swz));
        bf16x8 k1 = *(const bf16x8*)(kb + ((64 + g * 16) ^ swz));
        z = __builtin_amdgcn_mfma_f32_16x16x32_bf16(k0, qf[0], z, 0, 0, 0);
        z = __builtin_amdgcn_mfma_f32_16x16x32_bf16(k1, qf[1], z, 0, 0, 0);
        sacc[s] = z;
      } else {
        sacc[s] = f32x4{-INFINITY, -INFINITY, -INFINITY, -INFINITY};
      }
    }
    __builtin_amdgcn_s_setprio(0);
    if (partial) {
      #pragma unroll
      for (int s = 0; s < 4; ++s)
        #pragma unroll
        for (int r = 0; r < 4; ++r)
          if (s * 16 + g * 4 + r > wave * 16 + l16) sacc[s][r] = -INFINITY;
    }

    float v16[16];
    #pragma unroll
    for (int s = 0; s < 4; ++s)
      #pragma unroll
      for (int r = 0; r < 4; ++r) v16[s * 4 + r] = sacc[s][r];
    #pragma unroll
    for (int w = 8; w >= 1; w >>= 1)
      #pragma unroll
      for (int i = 0; i < 8; ++i)
        if (i < w) v16[i] = fmaxf(v16[i], v16[i + w]);
    float mx = v16[0];
    mx = fmaxf(mx, __shfl_xor(mx, 16, 64));
    mx = fmaxf(mx, __shfl_xor(mx, 32, 64));

    if (!__all(mx <= m_run + 8.0f)) {
      const float mn = fmaxf(m_run, mx);
      const float f  = __builtin_amdgcn_exp2f(m_run - mn);
      m_run = mn;
      l_run *= f;
      #pragma unroll
      for (int r = 0; r < 4; ++r) {
        const float fo = __shfl(f, g * 4 + r, 64);
        #pragma unroll
        for (int dt = 0; dt < 4; ++dt) o_acc[dt][r] *= fo;
      }
    }

    float pv16[16];
    bf16x8 pa[2];
    #pragma unroll
    for (int c = 0; c < 2; ++c)
      #pragma unroll
      for (int j = 0; j < 8; ++j) {
        const float pv = __builtin_amdgcn_exp2f(sacc[2 * c + (j >> 2)][j & 3] - m_run);
        pv16[c * 8 + j] = pv;
        pa[c][j] = (__bf16)pv;
      }
    #pragma unroll
    for (int w = 8; w >= 1; w >>= 1)
      #pragma unroll
      for (int i = 0; i < 8; ++i)
        if (i < w) pv16[i] += pv16[i + w];
    float sum = pv16[0];
    sum += __shfl_xor(sum, 16, 64);
    sum += __shfl_xor(sum, 32, 64);
    l_run += sum;

    __builtin_amdgcn_s_setprio(1);
    #pragma unroll
    for (int dt = 0; dt < 4; ++dt) {
      const int d = dt * 16 + l16;
      const int dx = (dt & 3) << 3;
      #pragma unroll
      for (int c = 0; c < 2; ++c) {
        const int kc0 = 8 * c + g;
        const int kc1 = 8 * c + 4 + g;
        union { bf16x8 v8; bf16x4 v4[2]; } uu;
        uu.v4[0] = *(const bf16x4*)((char*)Vt[cur] + kc0 * 512 + ((d * 8) ^ (kc0 << 3) ^ dx));
        uu.v4[1] = *(const bf16x4*)((char*)Vt[cur] + kc1 * 512 + ((d * 8) ^ (kc1 << 3) ^ dx));
        o_acc[dt] = __builtin_amdgcn_mfma_f32_16x16x32_bf16(pa[c], uu.v8, o_acc[dt], 0, 0, 0);
      }
    }
    __builtin_amdgcn_s_setprio(0);

    if (more) {
      const int nxt = cur ^ 1;
      #pragma unroll
      for (int hh = 0; hh < 2; ++hh) {
        const float* x0 = (const float*)&kreg[2 * hh];
        const float* x1 = (const float*)&kreg[2 * hh + 1];
        bf16x8 t;
        #pragma unroll
        for (int j = 0; j < 4; ++j) { t[j] = (__bf16)x0[j]; t[4 + j] = (__bf16)x1[j]; }
        *(bf16x8*)((char*)Kl[nxt] + krow * 128 + ((seg * 32 + hh * 16) ^ kswz)) = t;
      }
      #pragma unroll
      for (int i = 0; i < 4; ++i) {
        bf16x4 t;
        #pragma unroll
        for (int r = 0; r < 4; ++r) t[r] = (__bf16)((const float*)&vreg[r])[i];
        const int d = vdb * 4 + i;
        *(bf16x4*)((char*)Vt[nxt] + vkb * 512 + ((d * 8) ^ (vkb << 3) ^ vwx)) = t;
      }
    }
  }

  #pragma unroll
  for (int r = 0; r < 4; ++r) {
    const float il = __shfl(l_run, g * 4 + r, 64);
    const float inv = 1.f / il;
    float* orow = O + ((size_t)b * Tc + (q0 + g * 4 + r)) * (Hc * Dc) + h * Dc;
    #pragma unroll
    for (int dt = 0; dt < 4; ++dt)
      orow[dt * 16 + l16] = o_acc[dt][r] * inv;
  }
}

extern "C" void kernel_launch(void* const* d_in, const int* in_sizes, int n_in,
                              void* d_out, int out_size, void* d_ws, size_t ws_size,
                              hipStream_t stream) {
  const float* q = (const float*)d_in[0];
  const float* k = (const float*)d_in[1];
  const float* v = (const float*)d_in[2];
  float* out = (float*)d_out;

  if (ws_size >= WS_NEED_BYTES) {
    __bf16* k16 = (__bf16*)d_ws;
    __bf16* vq  = (__bf16*)((char*)d_ws + WS_K_BYTES);
    hipLaunchKernelGGL(conv_k, dim3(2048), dim3(256), 0, stream, k, k16);
    hipLaunchKernelGGL(conv_v, dim3(4096), dim3(256), 0, stream, v, vq);
    hipLaunchKernelGGL(attn_fwd_bf16s, dim3(1024), dim3(256), 0, stream,
                       q, k16, vq, out);
  } else {
    hipLaunchKernelGGL(attn_fwd_kernel, dim3(1024), dim3(256), 0, stream,
                       q, k, v, out);
  }
}